// Round 3
// baseline (3666.923 us; speedup 1.0000x reference)
//
#include <hip/hip_runtime.h>

typedef __attribute__((ext_vector_type(8))) short short8;
typedef __attribute__((ext_vector_type(4))) float floatx4;

#define B_DIM 64
#define L_SEQ 2048
#define D_H   64
#define BQ    16

// ---- LDS layout (bytes) ----
#define SC_BYTES  (BQ * L_SEQ * 2)          // 65536: scores/e, [16][2048] bf16, swizzled
#define RS_OFF    SC_BYTES                  // 64: row sums [16] f32
#define RI_OFF    (RS_OFF + 64)             // 64: row inv  [16] f32
#define LDS_TOTAL (RI_OFF + 64)             // 65664 -> 2 blocks/CU
// phase-2b combine buffer reuses the scores region (needs 8 KB)

__device__ __forceinline__ short f2bf(float f) {
    unsigned u = __builtin_bit_cast(unsigned, f);
    u += 0x7FFFu + ((u >> 16) & 1u);
    return (short)(u >> 16);
}
__device__ __forceinline__ float bf2f(short h) {
    unsigned u = ((unsigned)(unsigned short)h) << 16;
    return __builtin_bit_cast(float, u);
}
// 16B-slot XOR swizzle: even bank spread for b128 row-column access
__device__ __forceinline__ int sidx(int row, int colbyte) {
    return row * 4096 + (colbyte ^ ((row & 7) << 4));
}

__global__ __launch_bounds__(512, 4)
void sdpa_kernel(const float* __restrict__ q, const float* __restrict__ k,
                 const float* __restrict__ v, const void* __restrict__ mask,
                 float* __restrict__ out, float* __restrict__ attn)
{
    extern __shared__ char lds[];
    float* s_rsum = (float*)(lds + RS_OFF);
    float* s_rinv = (float*)(lds + RI_OFF);

    const int tid  = threadIdx.x;
    const int wave = tid >> 6;
    const int lane = tid & 63;
    const int l16  = lane & 15;
    const int l4   = lane >> 4;

    // bijective XCD swizzle: whole batches pinned to one XCD's L2
    const int bid  = blockIdx.x;                 // 8192 blocks, 8192%8==0
    const int sbid = (bid & 7) * 1024 + (bid >> 3);
    const int b     = sbid >> 7;                 // 128 blocks per batch
    const int qbase = (sbid & 127) * BQ;

    // ---------- mask element-size detection (uniform) ----------
    const unsigned* mwords = (const unsigned*)mask;
    bool wordMode = true;
    #pragma unroll 8
    for (int i = 0; i < 64; ++i) {
        unsigned w = mwords[i];
        if (!(w == 0u || w == 1u || w == 0x3F800000u)) wordMode = false;
    }

    // ---------- Phase 1: S = QK^T / 8 -> swizzled LDS (bf16) ----------
    short8 aq[2];
    {
        const float* qrow = q + ((size_t)b * L_SEQ + qbase + l16) * D_H + l4 * 8;
        #pragma unroll
        for (int h = 0; h < 2; ++h) {
            float4 f0 = *(const float4*)(qrow + h * 32);
            float4 f1 = *(const float4*)(qrow + h * 32 + 4);
            short8 a;
            a[0] = f2bf(f0.x); a[1] = f2bf(f0.y); a[2] = f2bf(f0.z); a[3] = f2bf(f0.w);
            a[4] = f2bf(f1.x); a[5] = f2bf(f1.y); a[6] = f2bf(f1.z); a[7] = f2bf(f1.w);
            aq[h] = a;
        }
    }
    const float* kbase = k + (size_t)b * L_SEQ * D_H;
    for (int tt = 0; tt < 4; ++tt) {
        float4 f[4][4];                          // 4 k-tiles' loads in flight
        #pragma unroll
        for (int u = 0; u < 4; ++u) {
            const int kt = wave * 16 + tt * 4 + u;
            const float* krow = kbase + ((size_t)(kt * 16 + l16)) * D_H + l4 * 8;
            f[u][0] = *(const float4*)(krow);
            f[u][1] = *(const float4*)(krow + 4);
            f[u][2] = *(const float4*)(krow + 32);
            f[u][3] = *(const float4*)(krow + 36);
        }
        #pragma unroll
        for (int u = 0; u < 4; ++u) {
            const int kt = wave * 16 + tt * 4 + u;
            floatx4 c = {0.f, 0.f, 0.f, 0.f};
            #pragma unroll
            for (int h = 0; h < 2; ++h) {
                short8 bk;
                bk[0] = f2bf(f[u][2*h].x); bk[1] = f2bf(f[u][2*h].y);
                bk[2] = f2bf(f[u][2*h].z); bk[3] = f2bf(f[u][2*h].w);
                bk[4] = f2bf(f[u][2*h+1].x); bk[5] = f2bf(f[u][2*h+1].y);
                bk[6] = f2bf(f[u][2*h+1].z); bk[7] = f2bf(f[u][2*h+1].w);
                c = __builtin_amdgcn_mfma_f32_16x16x32_bf16(aq[h], bk, c, 0, 0, 0);
            }
            #pragma unroll
            for (int r = 0; r < 4; ++r)
                *(short*)(lds + sidx(l4 * 4 + r, (kt * 16 + l16) * 2)) = f2bf(c[r] * 0.125f);
        }
    }
    __syncthreads();

    // ---------- Phase 2a: e = mask ? 0 : exp(s); row sums ----------
    const int qa = tid >> 5;                     // 0..15
    const int ca = tid & 31;                     // 32 threads/row
    const size_t rowbase = ((size_t)b * L_SEQ + qbase + qa) * (size_t)L_SEQ;

    short8 ev[8];
    float psum = 0.f;
    if (!wordMode) {
        uint2 mm[8];
        #pragma unroll
        for (int j = 0; j < 8; ++j)
            mm[j] = *(const uint2*)((const unsigned char*)mask + rowbase + ca * 8 + j * 256);
        #pragma unroll
        for (int j = 0; j < 8; ++j) {
            const int col = ca * 8 + j * 256;
            short8 sv = *(short8*)(lds + sidx(qa, col * 2));
            unsigned mbits = 0;
            #pragma unroll
            for (int i = 0; i < 4; ++i) {
                if ((mm[j].x >> (8 * i)) & 0xFFu) mbits |= (1u << i);
                if ((mm[j].y >> (8 * i)) & 0xFFu) mbits |= (1u << (i + 4));
            }
            float lsum = 0.f;
            #pragma unroll
            for (int i = 0; i < 8; ++i) {
                float s = bf2f(sv[i]);
                float e = ((mbits >> i) & 1u) ? 0.f : exp2f(s * 1.44269504f);
                short eb = f2bf(e);
                ev[j][i] = eb;
                lsum += bf2f(eb);
            }
            *(short8*)(lds + sidx(qa, col * 2)) = ev[j];
            psum += lsum;
        }
    } else {
        #pragma unroll 2
        for (int j = 0; j < 8; ++j) {
            const int col = ca * 8 + j * 256;
            short8 sv = *(short8*)(lds + sidx(qa, col * 2));
            const unsigned* mp = mwords + rowbase + col;
            uint4 a = *(const uint4*)mp;
            uint4 bb = *(const uint4*)(mp + 4);
            unsigned mbits =
                (a.x ? 1u : 0u) | (a.y ? 2u : 0u) | (a.z ? 4u : 0u) | (a.w ? 8u : 0u) |
                (bb.x ? 16u : 0u) | (bb.y ? 32u : 0u) | (bb.z ? 64u : 0u) | (bb.w ? 128u : 0u);
            float lsum = 0.f;
            #pragma unroll
            for (int i = 0; i < 8; ++i) {
                float s = bf2f(sv[i]);
                float e = ((mbits >> i) & 1u) ? 0.f : exp2f(s * 1.44269504f);
                short eb = f2bf(e);
                ev[j][i] = eb;
                lsum += bf2f(eb);
            }
            *(short8*)(lds + sidx(qa, col * 2)) = ev[j];
            psum += lsum;
        }
    }
    #pragma unroll
    for (int off = 1; off < 32; off <<= 1) psum += __shfl_xor(psum, off, 64);
    if (ca == 0) s_rsum[qa] = psum;
    __syncthreads();
    if (tid < 16) s_rinv[tid] = 1.0f / s_rsum[tid];
    __syncthreads();

    // ---------- attn write (from registers) ----------
    {
        const float ri = s_rinv[qa];
        float* arow = attn + rowbase;
        #pragma unroll 2
        for (int j = 0; j < 8; ++j) {
            const int col = ca * 8 + j * 256;
            float4 o0, o1;
            o0.x = bf2f(ev[j][0]) * ri; o0.y = bf2f(ev[j][1]) * ri;
            o0.z = bf2f(ev[j][2]) * ri; o0.w = bf2f(ev[j][3]) * ri;
            o1.x = bf2f(ev[j][4]) * ri; o1.y = bf2f(ev[j][5]) * ri;
            o1.z = bf2f(ev[j][6]) * ri; o1.w = bf2f(ev[j][7]) * ri;
            *(float4*)(arow + col)     = o0;
            *(float4*)(arow + col + 4) = o1;
        }
    }

    // ---------- Phase 2b: O = e·V, V fragments loaded DIRECT from global ----------
    const int dg = wave & 3;                     // d-group (16 cols)
    const int kh = wave >> 2;                    // k-half within 64-chunk
    floatx4 oacc = {0.f, 0.f, 0.f, 0.f};
    const float* vb = v + (size_t)b * L_SEQ * D_H + (size_t)(kh * 32 + l4 * 8) * D_H + dg * 16 + l16;

    for (int cc = 0; cc < 8; ++cc) {
        float vr[4][8];                          // 32 V loads in flight
        #pragma unroll
        for (int u = 0; u < 4; ++u) {
            const float* vp = vb + (size_t)(cc * 4 + u) * 64 * D_H;
            #pragma unroll
            for (int i = 0; i < 8; ++i) vr[u][i] = vp[i * D_H];
        }
        #pragma unroll
        for (int u = 0; u < 4; ++u) {
            const int ch = cc * 4 + u;
            short8 pf = *(short8*)(lds + sidx(l16, ch * 128 + kh * 64 + l4 * 16));
            short8 vf;
            #pragma unroll
            for (int i = 0; i < 8; ++i) vf[i] = f2bf(vr[u][i]);
            oacc = __builtin_amdgcn_mfma_f32_16x16x32_bf16(pf, vf, oacc, 0, 0, 0);
        }
    }

    // combine the two k-halves via LDS (reuse scores region as [2][16][64] f32)
    __syncthreads();
    float* s_ored = (float*)lds;
    #pragma unroll
    for (int r = 0; r < 4; ++r)
        s_ored[kh * 1024 + (l4 * 4 + r) * 64 + dg * 16 + l16] = oacc[r];
    __syncthreads();
    if (tid < 256) {
        const int qo = tid >> 4, dc = tid & 15;
        float4 a = *(float4*)(s_ored + qo * 64 + dc * 4);
        float4 c = *(float4*)(s_ored + 1024 + qo * 64 + dc * 4);
        const float ri = s_rinv[qo];
        float4 o;
        o.x = (a.x + c.x) * ri; o.y = (a.y + c.y) * ri;
        o.z = (a.z + c.z) * ri; o.w = (a.w + c.w) * ri;
        *(float4*)(out + ((size_t)b * L_SEQ + qbase + qo) * D_H + dc * 4) = o;
    }
}

extern "C" void kernel_launch(void* const* d_in, const int* in_sizes, int n_in,
                              void* d_out, int out_size, void* d_ws, size_t ws_size,
                              hipStream_t stream) {
    const float* q = (const float*)d_in[0];
    const float* k = (const float*)d_in[1];
    const float* v = (const float*)d_in[2];
    const void* mask = d_in[3];
    float* out  = (float*)d_out;
    float* attn = out + (size_t)B_DIM * L_SEQ * D_H;

    dim3 grid(B_DIM * (L_SEQ / BQ), 1, 1);       // 8192 blocks
    dim3 block(512, 1, 1);
    hipLaunchKernelGGL(sdpa_kernel, grid, block, LDS_TOTAL, stream,
                       q, k, v, mask, out, attn);
}

// Round 6
// 831.050 us; speedup vs baseline: 4.4124x; 4.4124x over previous
//
#include <hip/hip_runtime.h>

typedef __attribute__((ext_vector_type(8))) short short8;
typedef __attribute__((ext_vector_type(4))) float floatx4;
typedef __attribute__((ext_vector_type(4))) float fx4;
typedef __attribute__((ext_vector_type(4))) unsigned ux4;
typedef __attribute__((ext_vector_type(2))) unsigned ux2;

#define B_DIM 64
#define L_SEQ 2048
#define D_H   64
#define BQ    16
#define QK_SCALE 0.1803368801111137f   // log2(e)/8 : folded into Q in prepass

// ---- main-kernel LDS layout (bytes) ----
#define SC_BYTES  (BQ * L_SEQ * 2)          // 65536: scores/P [16][2048] bf16, swizzled
#define RS_OFF    SC_BYTES
#define RI_OFF    (RS_OFF + 64)
#define LDS_TOTAL (RI_OFF + 64)             // 65664 -> 2 blocks/CU

#if defined(__has_builtin)
#  if __has_builtin(__builtin_amdgcn_exp2f)
#    define EXP2(x) __builtin_amdgcn_exp2f(x)
#  else
#    define EXP2(x) exp2f(x)
#  endif
#else
#  define EXP2(x) exp2f(x)
#endif

__device__ __forceinline__ short f2bf(float f) {
    unsigned u = __builtin_bit_cast(unsigned, f);
    u += 0x7FFFu + ((u >> 16) & 1u);
    return (short)(u >> 16);
}
__device__ __forceinline__ float bf2f_lo(unsigned w) {
    return __builtin_bit_cast(float, w << 16);
}
__device__ __forceinline__ float bf2f_hi(unsigned w) {
    return __builtin_bit_cast(float, w & 0xFFFF0000u);
}
// packed RNE f32x2 -> bf16x2 (manual, trivially-copyable-safe)
__device__ __forceinline__ unsigned pk2bf(float a, float b) {
    unsigned ua = __builtin_bit_cast(unsigned, a);
    unsigned ub = __builtin_bit_cast(unsigned, b);
    ua += 0x7FFFu + ((ua >> 16) & 1u);
    ub += 0x7FFFu + ((ub >> 16) & 1u);
    return (ua >> 16) | (ub & 0xFFFF0000u);
}
// 16B-slot XOR swizzle
__device__ __forceinline__ int sidx(int row, int colbyte) {
    return row * 4096 + (colbyte ^ ((row & 7) << 4));
}

// ================= prepass 1: Q (pre-scaled) and K -> bf16 =================
__global__ __launch_bounds__(256) void prep_qk(const float* __restrict__ q,
                                               const float* __restrict__ k,
                                               unsigned short* __restrict__ qb,
                                               unsigned short* __restrict__ kb) {
    size_t i = (size_t)blockIdx.x * 256 + threadIdx.x;     // x4 elements
    fx4 q4 = __builtin_nontemporal_load((const fx4*)q + i);
    fx4 k4 = __builtin_nontemporal_load((const fx4*)k + i);
    ux2 qo, ko;
    qo[0] = pk2bf(q4[0] * QK_SCALE, q4[1] * QK_SCALE);
    qo[1] = pk2bf(q4[2] * QK_SCALE, q4[3] * QK_SCALE);
    ko[0] = pk2bf(k4[0], k4[1]);
    ko[1] = pk2bf(k4[2], k4[3]);
    *((ux2*)qb + i) = qo;
    *((ux2*)kb + i) = ko;
}

// ================= prepass 2: V -> bf16 transposed [B][D][L] =================
__global__ __launch_bounds__(256) void prep_vt(const float* __restrict__ v,
                                               unsigned short* __restrict__ vt) {
    __shared__ float tile[64][65];
    const int b  = blockIdx.x >> 5;
    const int kc = (blockIdx.x & 31) * 64;
    const int t  = threadIdx.x;
    {
        const int r = t >> 2, c4 = (t & 3) * 16;
        const float* src = v + ((size_t)b * L_SEQ + kc + r) * D_H + c4;
        #pragma unroll
        for (int j = 0; j < 4; ++j) {
            fx4 f = __builtin_nontemporal_load((const fx4*)(src + j * 4));
            tile[r][c4 + j * 4 + 0] = f[0]; tile[r][c4 + j * 4 + 1] = f[1];
            tile[r][c4 + j * 4 + 2] = f[2]; tile[r][c4 + j * 4 + 3] = f[3];
        }
    }
    __syncthreads();
    const int d = t >> 2, kq = (t & 3) * 16;
    ux4 o0, o1;
    o0[0] = pk2bf(tile[kq + 0][d], tile[kq + 1][d]);
    o0[1] = pk2bf(tile[kq + 2][d], tile[kq + 3][d]);
    o0[2] = pk2bf(tile[kq + 4][d], tile[kq + 5][d]);
    o0[3] = pk2bf(tile[kq + 6][d], tile[kq + 7][d]);
    o1[0] = pk2bf(tile[kq + 8][d], tile[kq + 9][d]);
    o1[1] = pk2bf(tile[kq +10][d], tile[kq +11][d]);
    o1[2] = pk2bf(tile[kq +12][d], tile[kq +13][d]);
    o1[3] = pk2bf(tile[kq +14][d], tile[kq +15][d]);
    unsigned short* dst = vt + ((size_t)b * D_H + d) * L_SEQ + kc + kq;
    *(ux4*)dst = o0;
    *(ux4*)(dst + 8) = o1;
}

// ================= main kernel =================
template <bool PRE>
__global__ __launch_bounds__(512, 4)
void sdpa_kernel(const float* __restrict__ qf, const float* __restrict__ kf,
                 const float* __restrict__ vf32, const void* __restrict__ mask,
                 const unsigned short* __restrict__ qb,
                 const unsigned short* __restrict__ kb,
                 const unsigned short* __restrict__ vt,
                 float* __restrict__ out, float* __restrict__ attn)
{
    extern __shared__ char lds[];
    float* s_rsum = (float*)(lds + RS_OFF);
    float* s_rinv = (float*)(lds + RI_OFF);

    const int tid  = threadIdx.x;
    const int wave = tid >> 6;
    const int lane = tid & 63;
    const int l16  = lane & 15;
    const int l4   = lane >> 4;

    const int bid  = blockIdx.x;                 // 8192, %8==0 -> bijective
    const int sbid = (bid & 7) * 1024 + (bid >> 3);
    const int b     = sbid >> 7;
    const int qbase = (sbid & 127) * BQ;

    // ---------- mask element-size detection (uniform) ----------
    const unsigned* mwords = (const unsigned*)mask;
    bool wordMode = true;
    #pragma unroll 8
    for (int i = 0; i < 64; ++i) {
        unsigned w = mwords[i];
        if (!(w == 0u || w == 1u || w == 0x3F800000u)) wordMode = false;
    }

    // ---------- Phase 1: S = (QK^T)*log2e/8 -> swizzled LDS bf16 ----------
    short8 aq0, aq1;
    if constexpr (PRE) {
        const unsigned short* qrow = qb + ((size_t)b * L_SEQ + qbase + l16) * D_H + l4 * 8;
        aq0 = *(const short8*)(qrow);
        aq1 = *(const short8*)(qrow + 32);
    } else {
        const float* qrow = qf + ((size_t)b * L_SEQ + qbase + l16) * D_H + l4 * 8;
        #pragma unroll
        for (int h = 0; h < 2; ++h) {
            float4 f0 = *(const float4*)(qrow + h * 32);
            float4 f1 = *(const float4*)(qrow + h * 32 + 4);
            short8 a;
            a[0] = f2bf(f0.x * QK_SCALE); a[1] = f2bf(f0.y * QK_SCALE);
            a[2] = f2bf(f0.z * QK_SCALE); a[3] = f2bf(f0.w * QK_SCALE);
            a[4] = f2bf(f1.x * QK_SCALE); a[5] = f2bf(f1.y * QK_SCALE);
            a[6] = f2bf(f1.z * QK_SCALE); a[7] = f2bf(f1.w * QK_SCALE);
            if (h == 0) aq0 = a; else aq1 = a;
        }
    }
    for (int t = 0; t < 16; ++t) {
        const int kt = wave * 16 + t;
        floatx4 c = {0.f, 0.f, 0.f, 0.f};
        if constexpr (PRE) {
            const unsigned short* krow = kb + ((size_t)b * L_SEQ + kt * 16 + l16) * D_H + l4 * 8;
            short8 b0 = *(const short8*)(krow);
            short8 b1 = *(const short8*)(krow + 32);
            c = __builtin_amdgcn_mfma_f32_16x16x32_bf16(aq0, b0, c, 0, 0, 0);
            c = __builtin_amdgcn_mfma_f32_16x16x32_bf16(aq1, b1, c, 0, 0, 0);
        } else {
            const float* krow = kf + ((size_t)b * L_SEQ + kt * 16 + l16) * D_H + l4 * 8;
            #pragma unroll
            for (int h = 0; h < 2; ++h) {
                float4 f0 = *(const float4*)(krow + h * 32);
                float4 f1 = *(const float4*)(krow + h * 32 + 4);
                short8 bk;
                bk[0] = f2bf(f0.x); bk[1] = f2bf(f0.y); bk[2] = f2bf(f0.z); bk[3] = f2bf(f0.w);
                bk[4] = f2bf(f1.x); bk[5] = f2bf(f1.y); bk[6] = f2bf(f1.z); bk[7] = f2bf(f1.w);
                c = __builtin_amdgcn_mfma_f32_16x16x32_bf16(h ? aq1 : aq0, bk, c, 0, 0, 0);
            }
        }
        #pragma unroll
        for (int r = 0; r < 4; ++r)
            *(short*)(lds + sidx(l4 * 4 + r, (kt * 16 + l16) * 2)) = f2bf(c[r]);
    }
    __syncthreads();

    // ---------- Phase 2a: e = mask ? 0 : exp2(s); f32 row sums; pack bf16 ----------
    const int qa = tid >> 5;
    const int ca = tid & 31;
    const size_t rowbase = ((size_t)b * L_SEQ + qbase + qa) * (size_t)L_SEQ;

    ux4 ev[8];
    float psum = 0.f;
    if (!wordMode) {
        ux2 mm[8];
        #pragma unroll
        for (int j = 0; j < 8; ++j)
            mm[j] = __builtin_nontemporal_load(
                (const ux2*)((const unsigned char*)mask + rowbase + ca * 8 + j * 256));
        #pragma unroll
        for (int j = 0; j < 8; ++j) {
            const int col = ca * 8 + j * 256;
            ux4 sw = *(ux4*)(lds + sidx(qa, col * 2));
            float e0 = EXP2(bf2f_lo(sw[0])), e1 = EXP2(bf2f_hi(sw[0]));
            float e2 = EXP2(bf2f_lo(sw[1])), e3 = EXP2(bf2f_hi(sw[1]));
            float e4 = EXP2(bf2f_lo(sw[2])), e5 = EXP2(bf2f_hi(sw[2]));
            float e6 = EXP2(bf2f_lo(sw[3])), e7 = EXP2(bf2f_hi(sw[3]));
            unsigned mx = mm[j][0], my = mm[j][1];
            e0 = (mx & 0x000000FFu) ? 0.f : e0;
            e1 = (mx & 0x0000FF00u) ? 0.f : e1;
            e2 = (mx & 0x00FF0000u) ? 0.f : e2;
            e3 = (mx & 0xFF000000u) ? 0.f : e3;
            e4 = (my & 0x000000FFu) ? 0.f : e4;
            e5 = (my & 0x0000FF00u) ? 0.f : e5;
            e6 = (my & 0x00FF0000u) ? 0.f : e6;
            e7 = (my & 0xFF000000u) ? 0.f : e7;
            psum += ((e0 + e1) + (e2 + e3)) + ((e4 + e5) + (e6 + e7));
            ev[j][0] = pk2bf(e0, e1); ev[j][1] = pk2bf(e2, e3);
            ev[j][2] = pk2bf(e4, e5); ev[j][3] = pk2bf(e6, e7);
            *(ux4*)(lds + sidx(qa, col * 2)) = ev[j];
        }
    } else {
        #pragma unroll 2
        for (int j = 0; j < 8; ++j) {
            const int col = ca * 8 + j * 256;
            ux4 sw = *(ux4*)(lds + sidx(qa, col * 2));
            const unsigned* mp = mwords + rowbase + col;
            ux4 ma = __builtin_nontemporal_load((const ux4*)mp);
            ux4 mb = __builtin_nontemporal_load((const ux4*)mp + 1);
            float e0 = EXP2(bf2f_lo(sw[0])), e1 = EXP2(bf2f_hi(sw[0]));
            float e2 = EXP2(bf2f_lo(sw[1])), e3 = EXP2(bf2f_hi(sw[1]));
            float e4 = EXP2(bf2f_lo(sw[2])), e5 = EXP2(bf2f_hi(sw[2]));
            float e6 = EXP2(bf2f_lo(sw[3])), e7 = EXP2(bf2f_hi(sw[3]));
            e0 = ma[0] ? 0.f : e0; e1 = ma[1] ? 0.f : e1;
            e2 = ma[2] ? 0.f : e2; e3 = ma[3] ? 0.f : e3;
            e4 = mb[0] ? 0.f : e4; e5 = mb[1] ? 0.f : e5;
            e6 = mb[2] ? 0.f : e6; e7 = mb[3] ? 0.f : e7;
            psum += ((e0 + e1) + (e2 + e3)) + ((e4 + e5) + (e6 + e7));
            ev[j][0] = pk2bf(e0, e1); ev[j][1] = pk2bf(e2, e3);
            ev[j][2] = pk2bf(e4, e5); ev[j][3] = pk2bf(e6, e7);
            *(ux4*)(lds + sidx(qa, col * 2)) = ev[j];
        }
    }
    #pragma unroll
    for (int off = 1; off < 32; off <<= 1) psum += __shfl_xor(psum, off, 64);
    if (ca == 0) s_rsum[qa] = psum;
    __syncthreads();
    if (tid < 16) s_rinv[tid] = 1.0f / s_rsum[tid];
    __syncthreads();

    // ---------- attn write (from registers, nontemporal) ----------
    {
        const float ri = s_rinv[qa];
        float* arow = attn + rowbase;
        #pragma unroll 2
        for (int j = 0; j < 8; ++j) {
            const int col = ca * 8 + j * 256;
            fx4 o0, o1;
            o0[0] = bf2f_lo(ev[j][0]) * ri; o0[1] = bf2f_hi(ev[j][0]) * ri;
            o0[2] = bf2f_lo(ev[j][1]) * ri; o0[3] = bf2f_hi(ev[j][1]) * ri;
            o1[0] = bf2f_lo(ev[j][2]) * ri; o1[1] = bf2f_hi(ev[j][2]) * ri;
            o1[2] = bf2f_lo(ev[j][3]) * ri; o1[3] = bf2f_hi(ev[j][3]) * ri;
            __builtin_nontemporal_store(o0, (fx4*)(arow + col));
            __builtin_nontemporal_store(o1, (fx4*)(arow + col + 4));
        }
    }

    // ---------- Phase 2b: O = P·V ----------
    const int dg = wave & 3;
    const int kh = wave >> 2;
    floatx4 oacc = {0.f, 0.f, 0.f, 0.f};

    if constexpr (PRE) {
        const unsigned short* vtb = vt + ((size_t)b * D_H + dg * 16 + l16) * L_SEQ + kh * 32 + l4 * 8;
        #pragma unroll 4
        for (int ch = 0; ch < 32; ++ch) {
            short8 vfr = *(const short8*)(vtb + ch * 64);
            short8 pf  = *(short8*)(lds + sidx(l16, ch * 128 + kh * 64 + l4 * 16));
            oacc = __builtin_amdgcn_mfma_f32_16x16x32_bf16(pf, vfr, oacc, 0, 0, 0);
        }
    } else {
        const float* vp0 = vf32 + ((size_t)b * L_SEQ + kh * 32 + l4 * 8) * D_H + dg * 16 + l16;
        for (int ch = 0; ch < 32; ++ch) {
            const float* vp = vp0 + (size_t)ch * 64 * D_H;
            short8 vfr;
            #pragma unroll
            for (int i = 0; i < 8; ++i) vfr[i] = f2bf(vp[i * D_H]);
            short8 pf = *(short8*)(lds + sidx(l16, ch * 128 + kh * 64 + l4 * 16));
            oacc = __builtin_amdgcn_mfma_f32_16x16x32_bf16(pf, vfr, oacc, 0, 0, 0);
        }
    }

    // combine k-halves (reuse scores LDS as [2][16][64] f32)
    __syncthreads();
    float* s_ored = (float*)lds;
    #pragma unroll
    for (int r = 0; r < 4; ++r)
        s_ored[kh * 1024 + (l4 * 4 + r) * 64 + dg * 16 + l16] = oacc[r];
    __syncthreads();
    if (tid < 256) {
        const int qo = tid >> 4, dc = tid & 15;
        float4 a = *(float4*)(s_ored + qo * 64 + dc * 4);
        float4 c = *(float4*)(s_ored + 1024 + qo * 64 + dc * 4);
        const float ri = s_rinv[qo];
        fx4 o;
        o[0] = (a.x + c.x) * ri; o[1] = (a.y + c.y) * ri;
        o[2] = (a.z + c.z) * ri; o[3] = (a.w + c.w) * ri;
        __builtin_nontemporal_store(o, (fx4*)(out + ((size_t)b * L_SEQ + qbase + qo) * D_H + dc * 4));
    }
}

extern "C" void kernel_launch(void* const* d_in, const int* in_sizes, int n_in,
                              void* d_out, int out_size, void* d_ws, size_t ws_size,
                              hipStream_t stream) {
    const float* q = (const float*)d_in[0];
    const float* k = (const float*)d_in[1];
    const float* v = (const float*)d_in[2];
    const void* mask = d_in[3];
    float* out  = (float*)d_out;
    float* attn = out + (size_t)B_DIM * L_SEQ * D_H;

    const size_t NE = (size_t)B_DIM * L_SEQ * D_H;          // 8,388,608
    dim3 grid(B_DIM * (L_SEQ / BQ), 1, 1);                  // 8192
    dim3 block(512, 1, 1);

    if (ws_size >= NE * 2 * 3) {
        unsigned short* qb = (unsigned short*)d_ws;
        unsigned short* kb = qb + NE;
        unsigned short* vt = kb + NE;
        hipLaunchKernelGGL(prep_qk, dim3(8192), dim3(256), 0, stream, q, k, qb, kb);
        hipLaunchKernelGGL(prep_vt, dim3(2048), dim3(256), 0, stream, v, vt);
        hipLaunchKernelGGL((sdpa_kernel<true>), grid, block, LDS_TOTAL, stream,
                           q, k, v, mask, qb, kb, vt, out, attn);
    } else {
        hipLaunchKernelGGL((sdpa_kernel<false>), grid, block, LDS_TOTAL, stream,
                           q, k, v, mask, (const unsigned short*)nullptr,
                           (const unsigned short*)nullptr, (const unsigned short*)nullptr,
                           out, attn);
    }
}

// Round 7
// 812.643 us; speedup vs baseline: 4.5123x; 1.0227x over previous
//
#include <hip/hip_runtime.h>

typedef __attribute__((ext_vector_type(8))) short short8;
typedef __attribute__((ext_vector_type(4))) float floatx4;
typedef __attribute__((ext_vector_type(4))) float fx4;
typedef __attribute__((ext_vector_type(4))) unsigned ux4;
typedef __attribute__((ext_vector_type(2))) unsigned ux2;

#define B_DIM 64
#define L_SEQ 2048
#define D_H   64
#define BQ    16
#define QK_SCALE 0.1803368801111137f   // log2(e)/8 : folded into Q

// ---- main-kernel LDS layout (bytes) ----
#define SC_BYTES  (BQ * L_SEQ * 2)          // 65536: scores/P [16][2048] bf16, swizzled
#define CB_OFF    SC_BYTES                  // 8192: combine buffer [2][16][64] f32
#define RI_OFF    (CB_OFF + 8192)           // 64: row inv [16] f32
#define LDS_TOTAL (RI_OFF + 64)             // 73792 -> 2 blocks/CU

#if defined(__has_builtin)
#  if __has_builtin(__builtin_amdgcn_exp2f)
#    define EXP2(x) __builtin_amdgcn_exp2f(x)
#  else
#    define EXP2(x) exp2f(x)
#  endif
#else
#  define EXP2(x) exp2f(x)
#endif

__device__ __forceinline__ short f2bf(float f) {
    unsigned u = __builtin_bit_cast(unsigned, f);
    u += 0x7FFFu + ((u >> 16) & 1u);
    return (short)(u >> 16);
}
__device__ __forceinline__ float bf2f_lo(unsigned w) {
    return __builtin_bit_cast(float, w << 16);
}
__device__ __forceinline__ float bf2f_hi(unsigned w) {
    return __builtin_bit_cast(float, w & 0xFFFF0000u);
}
__device__ __forceinline__ unsigned pk2bf(float a, float b) {
    unsigned ua = __builtin_bit_cast(unsigned, a);
    unsigned ub = __builtin_bit_cast(unsigned, b);
    ua += 0x7FFFu + ((ua >> 16) & 1u);
    ub += 0x7FFFu + ((ub >> 16) & 1u);
    return (ua >> 16) | (ub & 0xFFFF0000u);
}
// 16B-slot XOR swizzle
__device__ __forceinline__ int sidx(int row, int colbyte) {
    return row * 4096 + (colbyte ^ ((row & 7) << 4));
}

// ================= prepass 1: Q (pre-scaled) and K -> bf16 =================
__global__ __launch_bounds__(256) void prep_qk(const float* __restrict__ q,
                                               const float* __restrict__ k,
                                               unsigned short* __restrict__ qb,
                                               unsigned short* __restrict__ kb) {
    size_t i = (size_t)blockIdx.x * 256 + threadIdx.x;     // x4 elements
    fx4 q4 = __builtin_nontemporal_load((const fx4*)q + i);
    fx4 k4 = __builtin_nontemporal_load((const fx4*)k + i);
    ux2 qo, ko;
    qo[0] = pk2bf(q4[0] * QK_SCALE, q4[1] * QK_SCALE);
    qo[1] = pk2bf(q4[2] * QK_SCALE, q4[3] * QK_SCALE);
    ko[0] = pk2bf(k4[0], k4[1]);
    ko[1] = pk2bf(k4[2], k4[3]);
    *((ux2*)qb + i) = qo;
    *((ux2*)kb + i) = ko;
}

// ================= prepass 2: V -> bf16 transposed [B][D][L] =================
__global__ __launch_bounds__(256) void prep_vt(const float* __restrict__ v,
                                               unsigned short* __restrict__ vt) {
    __shared__ float tile[64][65];
    const int b  = blockIdx.x >> 5;
    const int kc = (blockIdx.x & 31) * 64;
    const int t  = threadIdx.x;
    {
        const int r = t >> 2, c4 = (t & 3) * 16;
        const float* src = v + ((size_t)b * L_SEQ + kc + r) * D_H + c4;
        #pragma unroll
        for (int j = 0; j < 4; ++j) {
            fx4 f = __builtin_nontemporal_load((const fx4*)(src + j * 4));
            tile[r][c4 + j * 4 + 0] = f[0]; tile[r][c4 + j * 4 + 1] = f[1];
            tile[r][c4 + j * 4 + 2] = f[2]; tile[r][c4 + j * 4 + 3] = f[3];
        }
    }
    __syncthreads();
    const int d = t >> 2, kq = (t & 3) * 16;
    ux4 o0, o1;
    o0[0] = pk2bf(tile[kq + 0][d], tile[kq + 1][d]);
    o0[1] = pk2bf(tile[kq + 2][d], tile[kq + 3][d]);
    o0[2] = pk2bf(tile[kq + 4][d], tile[kq + 5][d]);
    o0[3] = pk2bf(tile[kq + 6][d], tile[kq + 7][d]);
    o1[0] = pk2bf(tile[kq + 8][d], tile[kq + 9][d]);
    o1[1] = pk2bf(tile[kq +10][d], tile[kq +11][d]);
    o1[2] = pk2bf(tile[kq +12][d], tile[kq +13][d]);
    o1[3] = pk2bf(tile[kq +14][d], tile[kq +15][d]);
    unsigned short* dst = vt + ((size_t)b * D_H + d) * L_SEQ + kc + kq;
    *(ux4*)dst = o0;
    *(ux4*)(dst + 8) = o1;
}

// ================= main kernel =================
template <bool PRE>
__global__ __launch_bounds__(512, 4)
void sdpa_kernel(const float* __restrict__ qf, const float* __restrict__ kf,
                 const float* __restrict__ vf32, const void* __restrict__ mask,
                 const unsigned short* __restrict__ qb,
                 const unsigned short* __restrict__ kb,
                 const unsigned short* __restrict__ vt,
                 float* __restrict__ out, float* __restrict__ attn)
{
    extern __shared__ char lds[];
    float* s_rinv = (float*)(lds + RI_OFF);

    const int tid  = threadIdx.x;
    const int wave = tid >> 6;
    const int lane = tid & 63;
    const int l16  = lane & 15;
    const int l4   = lane >> 4;

    const int bid  = blockIdx.x;                 // 8192, %8==0 -> bijective
    const int sbid = (bid & 7) * 1024 + (bid >> 3);
    const int b     = sbid >> 7;
    const int qbase = (sbid & 127) * BQ;

    // ---------- mask element-size detection (uniform) ----------
    const unsigned* mwords = (const unsigned*)mask;
    bool wordMode = true;
    #pragma unroll 8
    for (int i = 0; i < 64; ++i) {
        unsigned w = mwords[i];
        if (!(w == 0u || w == 1u || w == 0x3F800000u)) wordMode = false;
    }

    const int qa = tid >> 5;                     // row for phase 2a
    const int ca = tid & 31;                     // 32 threads/row
    const size_t rowbase = ((size_t)b * L_SEQ + qbase + qa) * (size_t)L_SEQ;

    // ---------- byte-mode mask prefetch (hidden under phase 1) ----------
    ux2 mm[8];
    if (!wordMode) {
        #pragma unroll
        for (int j = 0; j < 8; ++j)
            mm[j] = __builtin_nontemporal_load(
                (const ux2*)((const unsigned char*)mask + rowbase + ca * 8 + j * 256));
    }

    // ---------- Phase 1: S = (QK^T)*log2e/8 -> swizzled LDS bf16 ----------
    short8 aq0, aq1;
    if constexpr (PRE) {
        const unsigned short* qrow = qb + ((size_t)b * L_SEQ + qbase + l16) * D_H + l4 * 8;
        aq0 = *(const short8*)(qrow);
        aq1 = *(const short8*)(qrow + 32);
    } else {
        const float* qrow = qf + ((size_t)b * L_SEQ + qbase + l16) * D_H + l4 * 8;
        #pragma unroll
        for (int h = 0; h < 2; ++h) {
            float4 f0 = *(const float4*)(qrow + h * 32);
            float4 f1 = *(const float4*)(qrow + h * 32 + 4);
            short8 a;
            a[0] = f2bf(f0.x * QK_SCALE); a[1] = f2bf(f0.y * QK_SCALE);
            a[2] = f2bf(f0.z * QK_SCALE); a[3] = f2bf(f0.w * QK_SCALE);
            a[4] = f2bf(f1.x * QK_SCALE); a[5] = f2bf(f1.y * QK_SCALE);
            a[6] = f2bf(f1.z * QK_SCALE); a[7] = f2bf(f1.w * QK_SCALE);
            if (h == 0) aq0 = a; else aq1 = a;
        }
    }
    #pragma unroll 2
    for (int t = 0; t < 16; ++t) {
        const int kt = wave * 16 + t;
        floatx4 c = {0.f, 0.f, 0.f, 0.f};
        if constexpr (PRE) {
            const unsigned short* krow = kb + ((size_t)b * L_SEQ + kt * 16 + l16) * D_H + l4 * 8;
            short8 b0 = *(const short8*)(krow);
            short8 b1 = *(const short8*)(krow + 32);
            c = __builtin_amdgcn_mfma_f32_16x16x32_bf16(aq0, b0, c, 0, 0, 0);
            c = __builtin_amdgcn_mfma_f32_16x16x32_bf16(aq1, b1, c, 0, 0, 0);
        } else {
            const float* krow = kf + ((size_t)b * L_SEQ + kt * 16 + l16) * D_H + l4 * 8;
            #pragma unroll
            for (int h = 0; h < 2; ++h) {
                float4 f0 = *(const float4*)(krow + h * 32);
                float4 f1 = *(const float4*)(krow + h * 32 + 4);
                short8 bk;
                bk[0] = f2bf(f0.x); bk[1] = f2bf(f0.y); bk[2] = f2bf(f0.z); bk[3] = f2bf(f0.w);
                bk[4] = f2bf(f1.x); bk[5] = f2bf(f1.y); bk[6] = f2bf(f1.z); bk[7] = f2bf(f1.w);
                c = __builtin_amdgcn_mfma_f32_16x16x32_bf16(h ? aq1 : aq0, bk, c, 0, 0, 0);
            }
        }
        #pragma unroll
        for (int r = 0; r < 4; ++r)
            *(short*)(lds + sidx(l4 * 4 + r, (kt * 16 + l16) * 2)) = f2bf(c[r]);
    }
    __syncthreads();                             // barrier 1: scores ready

    // ---------- Phase 2a: e = mask ? 0 : exp2(s); f32 row sums; pack bf16 ----------
    ux4 ev[8];
    float psum = 0.f;
    if (!wordMode) {
        #pragma unroll 2
        for (int j = 0; j < 8; ++j) {
            const int col = ca * 8 + j * 256;
            ux4 sw = *(ux4*)(lds + sidx(qa, col * 2));
            float e0 = EXP2(bf2f_lo(sw[0])), e1 = EXP2(bf2f_hi(sw[0]));
            float e2 = EXP2(bf2f_lo(sw[1])), e3 = EXP2(bf2f_hi(sw[1]));
            float e4 = EXP2(bf2f_lo(sw[2])), e5 = EXP2(bf2f_hi(sw[2]));
            float e6 = EXP2(bf2f_lo(sw[3])), e7 = EXP2(bf2f_hi(sw[3]));
            unsigned mx = mm[j][0], my = mm[j][1];
            e0 = (mx & 0x000000FFu) ? 0.f : e0;
            e1 = (mx & 0x0000FF00u) ? 0.f : e1;
            e2 = (mx & 0x00FF0000u) ? 0.f : e2;
            e3 = (mx & 0xFF000000u) ? 0.f : e3;
            e4 = (my & 0x000000FFu) ? 0.f : e4;
            e5 = (my & 0x0000FF00u) ? 0.f : e5;
            e6 = (my & 0x00FF0000u) ? 0.f : e6;
            e7 = (my & 0xFF000000u) ? 0.f : e7;
            psum += ((e0 + e1) + (e2 + e3)) + ((e4 + e5) + (e6 + e7));
            ev[j][0] = pk2bf(e0, e1); ev[j][1] = pk2bf(e2, e3);
            ev[j][2] = pk2bf(e4, e5); ev[j][3] = pk2bf(e6, e7);
            *(ux4*)(lds + sidx(qa, col * 2)) = ev[j];
        }
    } else {
        #pragma unroll 2
        for (int j = 0; j < 8; ++j) {
            const int col = ca * 8 + j * 256;
            ux4 sw = *(ux4*)(lds + sidx(qa, col * 2));
            const unsigned* mp = mwords + rowbase + col;
            ux4 ma = __builtin_nontemporal_load((const ux4*)mp);
            ux4 mb = __builtin_nontemporal_load((const ux4*)mp + 1);
            float e0 = EXP2(bf2f_lo(sw[0])), e1 = EXP2(bf2f_hi(sw[0]));
            float e2 = EXP2(bf2f_lo(sw[1])), e3 = EXP2(bf2f_hi(sw[1]));
            float e4 = EXP2(bf2f_lo(sw[2])), e5 = EXP2(bf2f_hi(sw[2]));
            float e6 = EXP2(bf2f_lo(sw[3])), e7 = EXP2(bf2f_hi(sw[3]));
            e0 = ma[0] ? 0.f : e0; e1 = ma[1] ? 0.f : e1;
            e2 = ma[2] ? 0.f : e2; e3 = ma[3] ? 0.f : e3;
            e4 = mb[0] ? 0.f : e4; e5 = mb[1] ? 0.f : e5;
            e6 = mb[2] ? 0.f : e6; e7 = mb[3] ? 0.f : e7;
            psum += ((e0 + e1) + (e2 + e3)) + ((e4 + e5) + (e6 + e7));
            ev[j][0] = pk2bf(e0, e1); ev[j][1] = pk2bf(e2, e3);
            ev[j][2] = pk2bf(e4, e5); ev[j][3] = pk2bf(e6, e7);
            *(ux4*)(lds + sidx(qa, col * 2)) = ev[j];
        }
    }
    // 32-lane butterfly: every lane ends with its row's full sum -> local ri
    #pragma unroll
    for (int off = 1; off < 32; off <<= 1) psum += __shfl_xor(psum, off, 64);
    const float ri = 1.0f / psum;
    if (ca == 0) s_rinv[qa] = ri;                // for the epilogue only

    // ---------- attn write (registers, no barrier needed) ----------
    {
        float* arow = attn + rowbase;
        #pragma unroll 2
        for (int j = 0; j < 8; ++j) {
            const int col = ca * 8 + j * 256;
            fx4 o0, o1;
            o0[0] = bf2f_lo(ev[j][0]) * ri; o0[1] = bf2f_hi(ev[j][0]) * ri;
            o0[2] = bf2f_lo(ev[j][1]) * ri; o0[3] = bf2f_hi(ev[j][1]) * ri;
            o1[0] = bf2f_lo(ev[j][2]) * ri; o1[1] = bf2f_hi(ev[j][2]) * ri;
            o1[2] = bf2f_lo(ev[j][3]) * ri; o1[3] = bf2f_hi(ev[j][3]) * ri;
            *(fx4*)(arow + col)     = o0;        // regular stores: L2 write-combining
            *(fx4*)(arow + col + 4) = o1;
        }
    }
    __syncthreads();                             // barrier 2: e-LDS complete before P2b reads

    // ---------- Phase 2b: O = P·V (depth-4 software pipeline) ----------
    const int dg = wave & 3;
    const int kh = wave >> 2;
    floatx4 oacc = {0.f, 0.f, 0.f, 0.f};

    if constexpr (PRE) {
        const unsigned short* vtb = vt + ((size_t)b * D_H + dg * 16 + l16) * L_SEQ + kh * 32 + l4 * 8;
        short8 vb0 = *(const short8*)(vtb);
        short8 vb1 = *(const short8*)(vtb + 64);
        short8 vb2 = *(const short8*)(vtb + 128);
        short8 vb3 = *(const short8*)(vtb + 192);
        for (int cc = 0; cc < 8; ++cc) {
            short8 vn0, vn1, vn2, vn3;
            if (cc < 7) {                        // issue next group's loads first
                const unsigned short* vp = vtb + (cc + 1) * 256;
                vn0 = *(const short8*)(vp);
                vn1 = *(const short8*)(vp + 64);
                vn2 = *(const short8*)(vp + 128);
                vn3 = *(const short8*)(vp + 192);
            } else {
                vn0 = vb0; vn1 = vb1; vn2 = vb2; vn3 = vb3;
            }
            const int kbase2 = cc * 512 + kh * 64 + l4 * 16;
            short8 pf0 = *(short8*)(lds + sidx(l16, kbase2));
            oacc = __builtin_amdgcn_mfma_f32_16x16x32_bf16(pf0, vb0, oacc, 0, 0, 0);
            short8 pf1 = *(short8*)(lds + sidx(l16, kbase2 + 128));
            oacc = __builtin_amdgcn_mfma_f32_16x16x32_bf16(pf1, vb1, oacc, 0, 0, 0);
            short8 pf2 = *(short8*)(lds + sidx(l16, kbase2 + 256));
            oacc = __builtin_amdgcn_mfma_f32_16x16x32_bf16(pf2, vb2, oacc, 0, 0, 0);
            short8 pf3 = *(short8*)(lds + sidx(l16, kbase2 + 384));
            oacc = __builtin_amdgcn_mfma_f32_16x16x32_bf16(pf3, vb3, oacc, 0, 0, 0);
            vb0 = vn0; vb1 = vn1; vb2 = vn2; vb3 = vn3;
        }
    } else {
        const float* vp0 = vf32 + ((size_t)b * L_SEQ + kh * 32 + l4 * 8) * D_H + dg * 16 + l16;
        for (int ch = 0; ch < 32; ++ch) {
            const float* vp = vp0 + (size_t)ch * 64 * D_H;
            short8 vfr;
            #pragma unroll
            for (int i = 0; i < 8; ++i) vfr[i] = f2bf(vp[i * D_H]);
            short8 pf = *(short8*)(lds + sidx(l16, ch * 128 + kh * 64 + l4 * 16));
            oacc = __builtin_amdgcn_mfma_f32_16x16x32_bf16(pf, vfr, oacc, 0, 0, 0);
        }
    }

    // combine k-halves in separate buffer (scores untouched -> one barrier only)
    float* s_comb = (float*)(lds + CB_OFF);
    #pragma unroll
    for (int r = 0; r < 4; ++r)
        s_comb[kh * 1024 + (l4 * 4 + r) * 64 + dg * 16 + l16] = oacc[r];
    __syncthreads();                             // barrier 3: combine ready
    if (tid < 256) {
        const int qo = tid >> 4, dc = tid & 15;
        float4 a = *(float4*)(s_comb + qo * 64 + dc * 4);
        float4 c = *(float4*)(s_comb + 1024 + qo * 64 + dc * 4);
        const float rio = s_rinv[qo];
        fx4 o;
        o[0] = (a.x + c.x) * rio; o[1] = (a.y + c.y) * rio;
        o[2] = (a.z + c.z) * rio; o[3] = (a.w + c.w) * rio;
        *(fx4*)(out + ((size_t)b * L_SEQ + qbase + qo) * D_H + dc * 4) = o;
    }
}

extern "C" void kernel_launch(void* const* d_in, const int* in_sizes, int n_in,
                              void* d_out, int out_size, void* d_ws, size_t ws_size,
                              hipStream_t stream) {
    const float* q = (const float*)d_in[0];
    const float* k = (const float*)d_in[1];
    const float* v = (const float*)d_in[2];
    const void* mask = d_in[3];
    float* out  = (float*)d_out;
    float* attn = out + (size_t)B_DIM * L_SEQ * D_H;

    const size_t NE = (size_t)B_DIM * L_SEQ * D_H;          // 8,388,608
    dim3 grid(B_DIM * (L_SEQ / BQ), 1, 1);                  // 8192
    dim3 block(512, 1, 1);

    if (ws_size >= NE * 2 * 3) {
        unsigned short* qb = (unsigned short*)d_ws;
        unsigned short* kb = qb + NE;
        unsigned short* vt = kb + NE;
        hipLaunchKernelGGL(prep_qk, dim3(8192), dim3(256), 0, stream, q, k, qb, kb);
        hipLaunchKernelGGL(prep_vt, dim3(2048), dim3(256), 0, stream, v, vt);
        hipLaunchKernelGGL((sdpa_kernel<true>), grid, block, LDS_TOTAL, stream,
                           q, k, v, mask, qb, kb, vt, out, attn);
    } else {
        hipLaunchKernelGGL((sdpa_kernel<false>), grid, block, LDS_TOTAL, stream,
                           q, k, v, mask, (const unsigned short*)nullptr,
                           (const unsigned short*)nullptr, (const unsigned short*)nullptr,
                           out, attn);
    }
}